// Round 1
// baseline (373.058 us; speedup 1.0000x reference)
//
#include <hip/hip_runtime.h>
#include <hip/hip_bf16.h>
#include <stdint.h>

#define B_   4
#define S_   1024
#define H_   1024      // hidden
#define NH_  16        // ENT
#define D_   64        // INNER
#define N1_  2048      // ENT*2*INNER
#define M1_  4096      // B*S
#define NEG_ 1000000000000.0f

typedef __attribute__((ext_vector_type(8))) short bf16x8;
typedef __attribute__((ext_vector_type(4))) float f32x4;

__device__ inline void gload_lds16(const void* g, void* l) {
  __builtin_amdgcn_global_load_lds(
      (const __attribute__((address_space(1))) unsigned int*)g,
      (__attribute__((address_space(3))) unsigned int*)l, 16, 0, 0);
}

__device__ inline unsigned short f2bf(float f) {
  union { float f; uint32_t u; } a; a.f = f;
  uint32_t r = a.u + 0x7fff + ((a.u >> 16) & 1);   // RNE
  return (unsigned short)(r >> 16);
}

// ---------------- prep kernels ----------------

__global__ void k_cast(const float4* __restrict__ in, unsigned short* __restrict__ out, int n4) {
  int i = blockIdx.x * 256 + threadIdx.x;
  if (i >= n4) return;
  float4 v = in[i];
  uint64_t pk = (uint64_t)f2bf(v.x) | ((uint64_t)f2bf(v.y) << 16) |
                ((uint64_t)f2bf(v.z) << 32) | ((uint64_t)f2bf(v.w) << 48);
  ((uint64_t*)out)[i] = pk;
}

// W (H_ x N1_) fp32 -> WT (N1_ x H_) bf16
__global__ void k_transW(const float* __restrict__ W, unsigned short* __restrict__ WT) {
  __shared__ float t[32][33];
  int nb = blockIdx.x * 32, kb = blockIdx.y * 32;
  int tx = threadIdx.x, ty = threadIdx.y;   // (32, 8)
  for (int r = 0; r < 4; r++)
    t[ty + r * 8][tx] = W[(size_t)(kb + ty + r * 8) * N1_ + nb + tx];
  __syncthreads();
  for (int r = 0; r < 4; r++)
    WT[(size_t)(nb + ty + r * 8) * H_ + kb + tx] = f2bf(t[tx][ty + r * 8]);
}

// sin/cos table: tab[(pos*32+fi)*2] = sin, +1 = cos
__global__ void k_sincos(float* __restrict__ tab) {
  int i = blockIdx.x * 256 + threadIdx.x;  // 0..32767
  if (i >= S_ * 32) return;
  int pos = i >> 5, fi = i & 31;
  float freq = exp2f(-(float)fi * (13.2877123795494f / 32.0f)); // 10000^(-2fi/64)
  float ang = (float)pos * freq;
  tab[2 * i]     = sinf(ang);
  tab[2 * i + 1] = cosf(ang);
}

// ---------------- stage 1: P = lhs @ W + b, fused RoPE, scatter to q/k ----------------

__global__ __launch_bounds__(256) void k_gemm1(
    const unsigned short* __restrict__ A,   // M1_ x H_ bf16
    const unsigned short* __restrict__ BT,  // N1_ x H_ bf16
    const float* __restrict__ bias,         // N1_
    const float* __restrict__ sc,           // sin/cos table
    unsigned short* __restrict__ qws,       // [B*NH][S][D] bf16
    unsigned short* __restrict__ kws) {
  __shared__ unsigned short a_lds[128 * 32];
  __shared__ unsigned short b_lds[128 * 32];
  int t = threadIdx.x;
  int lane = t & 63, wv = t >> 6;
  int wm = wv >> 1, wn = wv & 1;
  int col = lane & 15, quad = lane >> 4;
  int mBase = blockIdx.y * 128, nBase = blockIdx.x * 128;

  f32x4 acc[4][4] = {};

  for (int kk = 0; kk < H_; kk += 32) {
    for (int c = 0; c < 2; c++) {
      int idx = c * 256 + t;
      int r = idx >> 2, ch = idx & 3;
      gload_lds16(A + (size_t)(mBase + r) * H_ + kk + ch * 8, a_lds + idx * 8);
      gload_lds16(BT + (size_t)(nBase + r) * H_ + kk + ch * 8, b_lds + idx * 8);
    }
    __syncthreads();
    bf16x8 af[4], bf[4];
#pragma unroll
    for (int i = 0; i < 4; i++)
      af[i] = *(const bf16x8*)&a_lds[(wm * 64 + i * 16 + col) * 32 + quad * 8];
#pragma unroll
    for (int j = 0; j < 4; j++)
      bf[j] = *(const bf16x8*)&b_lds[(wn * 64 + j * 16 + col) * 32 + quad * 8];
#pragma unroll
    for (int i = 0; i < 4; i++)
#pragma unroll
      for (int j = 0; j < 4; j++)
        acc[i][j] = __builtin_amdgcn_mfma_f32_16x16x32_bf16(af[i], bf[j], acc[i][j], 0, 0, 0);
    __syncthreads();
  }

  // epilogue: bias + RoPE (interleaved) + scatter to [B*NH][S][D]
#pragma unroll
  for (int j = 0; j < 4; j++) {
    int n = nBase + wn * 64 + j * 16 + col;    // 0..2047
    float bj = bias[n];
    int d = n & 63;
    int fi = d >> 1;
    int head = n >> 7;
    int isK = (n >> 6) & 1;
    unsigned short* dst = isK ? kws : qws;
#pragma unroll
    for (int i = 0; i < 4; i++) {
#pragma unroll
      for (int rg = 0; rg < 4; rg++) {
        int m = mBase + wm * 64 + i * 16 + quad * 4 + rg;   // 0..4095
        float v = acc[i][j][rg] + bj;
        float p = __shfl_xor(v, 1, 64);   // partner element of the RoPE pair
        int pos = m & (S_ - 1);
        float sv = sc[(pos * 32 + fi) * 2];
        float cv = sc[(pos * 32 + fi) * 2 + 1];
        float o = (d & 1) ? (v * cv + p * sv) : (v * cv - p * sv);
        int bb = m >> 10, ss = m & (S_ - 1);
        dst[((size_t)(bb * NH_ + head) * S_ + ss) * D_ + d] = f2bf(o);
      }
    }
  }
}

// ---------------- stage 2: logits[b,h] = Q K^T with masks ----------------

__global__ __launch_bounds__(256) void k_gemm2(
    const unsigned short* __restrict__ qws,
    const unsigned short* __restrict__ kws,
    const float* __restrict__ tl,           // (B, S)
    float* __restrict__ out) {
  __shared__ unsigned short q_lds[128 * 64];
  __shared__ unsigned short k_lds[128 * 64];
  int t = threadIdx.x;
  int lane = t & 63, wv = t >> 6, wm = wv >> 1, wn = wv & 1;
  int col = lane & 15, quad = lane >> 4;
  int z = blockIdx.z;                       // b*16+h
  int mT = blockIdx.y * 128, nT = blockIdx.x * 128;
  const unsigned short* qb = qws + ((size_t)z * S_ + mT) * D_;  // contiguous 16KB
  const unsigned short* kb = kws + ((size_t)z * S_ + nT) * D_;

  for (int c = 0; c < 4; c++) {
    int idx = c * 256 + t;
    gload_lds16(qb + idx * 8, q_lds + idx * 8);
    gload_lds16(kb + idx * 8, k_lds + idx * 8);
  }
  __syncthreads();

  f32x4 acc[4][4] = {};
#pragma unroll
  for (int kk = 0; kk < 64; kk += 32) {
    bf16x8 af[4], bf[4];
#pragma unroll
    for (int i = 0; i < 4; i++)
      af[i] = *(const bf16x8*)&q_lds[(wm * 64 + i * 16 + col) * 64 + kk + quad * 8];
#pragma unroll
    for (int j = 0; j < 4; j++)
      bf[j] = *(const bf16x8*)&k_lds[(wn * 64 + j * 16 + col) * 64 + kk + quad * 8];
#pragma unroll
    for (int i = 0; i < 4; i++)
#pragma unroll
      for (int j = 0; j < 4; j++)
        acc[i][j] = __builtin_amdgcn_mfma_f32_16x16x32_bf16(af[i], bf[j], acc[i][j], 0, 0, 0);
  }

  int bb = z >> 4;
#pragma unroll
  for (int j = 0; j < 4; j++) {
    int n = nT + wn * 64 + j * 16 + col;
    float pad = tl[bb * S_ + n];
    float negterm = (1.0f - pad) * NEG_;
#pragma unroll
    for (int i = 0; i < 4; i++) {
      int mb = mT + wm * 64 + i * 16 + quad * 4;
#pragma unroll
      for (int rg = 0; rg < 4; rg++) {
        int m = mb + rg;
        float v = acc[i][j][rg];
        v = v * pad - negterm;
        if (m > n) v -= NEG_;
        v *= 0.125f;                        // 1/sqrt(64)
        out[((size_t)z * S_ + m) * S_ + n] = v;
      }
    }
  }
}

// ---------------- launch ----------------

extern "C" void kernel_launch(void* const* d_in, const int* in_sizes, int n_in,
                              void* d_out, int out_size, void* d_ws, size_t ws_size,
                              hipStream_t stream) {
  const float* lhs  = (const float*)d_in[0];   // (4,1024,1024)
  const float* W    = (const float*)d_in[1];   // (1024,2048)
  const float* bias = (const float*)d_in[2];   // (2048,)
  const float* tl   = (const float*)d_in[3];   // (4,1024)
  float* out = (float*)d_out;

  char* ws = (char*)d_ws;
  unsigned short* lhsb = (unsigned short*)(ws);                      // 8 MB
  unsigned short* WT   = (unsigned short*)(ws + (8u  << 20));        // 4 MB
  unsigned short* qws  = (unsigned short*)(ws + (12u << 20));        // 8 MB
  unsigned short* kws  = (unsigned short*)(ws + (20u << 20));        // 8 MB
  float*          sc   = (float*)        (ws + (28u << 20));         // 256 KB

  k_cast<<<(M1_ * H_ / 4 + 255) / 256, 256, 0, stream>>>((const float4*)lhs, lhsb, M1_ * H_ / 4);
  k_transW<<<dim3(N1_ / 32, H_ / 32), dim3(32, 8), 0, stream>>>(W, WT);
  k_sincos<<<(S_ * 32 + 255) / 256, 256, 0, stream>>>(sc);
  k_gemm1<<<dim3(N1_ / 128, M1_ / 128), 256, 0, stream>>>(lhsb, WT, bias, sc, qws, kws);
  k_gemm2<<<dim3(S_ / 128, S_ / 128, B_ * NH_), 256, 0, stream>>>(qws, kws, tl, out);
}